// Round 19
// baseline (40.797 us; speedup 1.0000x reference)
//
#include <hip/hip_runtime.h>

#define B_SZ 1024
#define F_SZ 512
#define NK   50
#define KD   5
#define C_SZ 250              // NK*KD
#define OUTW 562              // F_SZ + NK
#define PLANE (C_SZ * B_SZ)   // SoA M plane: [col c=k*5+d][row], 256000 floats
#define NT   16               // 16 row-tiles of 64
#define TILE 64
#define NPAIRS 136            // NT*(NT+1)/2 unordered tile pairs
#define PBLK  34              // tile pairs per block (4 waves x 34 blocks = 136)
#define PART_ELEMS (NK * NT * B_SZ)   // 819200 floats
#define LOG2E 1.44269504088896340736f

// ---------------------------------------------------------------------------
// K1: fused GEMM + copy (round-9 version — measured best). grid 384 x 256.
//  blocks [0,256):   M = x@T scaled by log2e, SoA planes ws2[ks][c][row].
//                    rt = blk&127 (8 rows), ks = blk>>7 (256 f each).
//  blocks [256,384): copy x rows into out (float2), 8 rows/block.
// ---------------------------------------------------------------------------
__global__ __launch_bounds__(256) void gemm_copy_kernel(const float* __restrict__ x,
                                                        const float* __restrict__ T,
                                                        float* __restrict__ ws2,
                                                        float* __restrict__ out,
                                                        int zero_feat) {
    const int t = threadIdx.x;

    if (blockIdx.x >= 256) {                 // ---- copy path
        const int b = blockIdx.x - 256;      // 0..127
#pragma unroll
        for (int r = 0; r < 8; ++r) {
            const int row = b * 8 + r;
            const float2* src = (const float2*)(x + (size_t)row * F_SZ);
            float2* dst = (float2*)(out + (size_t)row * OUTW);
            dst[t] = src[t];
            if (zero_feat && t < NK) out[(size_t)row * OUTW + F_SZ + t] = 0.0f;
        }
        return;
    }

    // ---- gemm path
    const int rt = blockIdx.x & 127;         // 8-row tile
    const int ks = blockIdx.x >> 7;          // k-split (0,1)
    if (t >= C_SZ) return;                   // no __syncthreads in this path
    const int r0 = rt * 8;
    const int f0 = ks * 256;

    float acc[8] = {0.f, 0.f, 0.f, 0.f, 0.f, 0.f, 0.f, 0.f};
    const float* xp = x + (size_t)r0 * F_SZ + f0;     // block-uniform base
    const float* Tp = T + (size_t)f0 * C_SZ + t;

#pragma unroll 8
    for (int f = 0; f < 256; ++f) {
        const float tv = Tp[(size_t)f * C_SZ];
#pragma unroll
        for (int r = 0; r < 8; ++r)
            acc[r] += xp[r * F_SZ + f] * tv;          // uniform -> s_load
    }

    float* dst = ws2 + ((size_t)(ks * C_SZ + t)) * B_SZ + r0;   // 32B aligned
    float4 lo = make_float4(acc[0] * LOG2E, acc[1] * LOG2E,
                            acc[2] * LOG2E, acc[3] * LOG2E);
    float4 hi = make_float4(acc[4] * LOG2E, acc[5] * LOG2E,
                            acc[6] * LOG2E, acc[7] * LOG2E);
    ((float4*)dst)[0] = lo;
    ((float4*)dst)[1] = hi;
}

// ---------------------------------------------------------------------------
// K2: pair_v3 — 16 i-lanes x 4 j-groups per wave; each wave owns ONE (ti,tj)
// 64x64 tile. (r18 lesson: pair's ~11us = LDS traffic artifact of lane=row
// layout: 80KB broadcast qj + 32KB et per block. This layout needs neither.)
//   - lane (jg = lane>>4, il = lane&15): rows bi+il*4..+3 in registers
//     (float4 coalesced global loads); j's = bj+jg*16..+15 read as float4
//     c-vectors from GLOBAL (L2-hit; 4 distinct addrs/wave, 16-lane bcast).
//   - row sums: acci[4] regs + 2 shfl_xor (lanes ^16,^32) -> lane (jg,il)
//     stores row bi+il*4+jg. One 256B store per wave.
//   - col sums: colacc[16] regs (lane's 4 rows) -> cross-il reduce through
//     tiny padded LDS colw[wv][64][17] (16 w + 16 r, conflict-free, wave-
//     local -> NO barriers). Skipped on diagonal tiles.
// grid 1700 = 50 k x 34; 256 thr. Partials part[k][src_tile][row] as r9.
// ---------------------------------------------------------------------------
template <bool ATOMIC>
__global__ __launch_bounds__(256) void pair_kernel(const float* __restrict__ ws2,
                                                   float* __restrict__ part,
                                                   float* __restrict__ out) {
    __shared__ float colw[4][TILE][17];      // per-wave region, 17.4 KB

    const int bid  = blockIdx.x;
    const int k    = bid / PBLK;
    const int wv   = __builtin_amdgcn_readfirstlane(threadIdx.x >> 6);
    const int lane = threadIdx.x & 63;
    const int jg   = lane >> 4;              // 0..3
    const int il   = lane & 15;              // 0..15

    int p = (bid - k * PBLK) * 4 + wv;       // 0..135
    int ti = 0;
    while (p >= NT - ti) { p -= NT - ti; ++ti; }
    const int tj = ti + p;
    const int bi = ti * TILE, bj = tj * TILE;
    const bool diag = (ti == tj);

    const float* pa = ws2 + (size_t)k * (KD * B_SZ);  // plane 0, cols k*5..
    const float* pb = pa + (size_t)PLANE;             // plane 1

    // i-side: 4 rows (bi + il*4 + r) x 5 dims, register-resident
    float mi[4][KD];
#pragma unroll
    for (int d = 0; d < KD; ++d) {
        const float4 a = *(const float4*)(pa + d * B_SZ + bi + il * 4);
        const float4 b = *(const float4*)(pb + d * B_SZ + bi + il * 4);
        mi[0][d] = a.x + b.x; mi[1][d] = a.y + b.y;
        mi[2][d] = a.z + b.z; mi[3][d] = a.w + b.w;
    }

    float acci[4] = {0.f, 0.f, 0.f, 0.f};    // row sums over this jg's 16 j
    float colacc[16];                        // col sums over this lane's 4 rows
#pragma unroll
    for (int q = 0; q < 16; ++q) colacc[q] = 0.0f;

#pragma unroll
    for (int c4 = 0; c4 < 4; ++c4) {
        const int jb = bj + jg * 16 + c4 * 4;
        float4 cj[KD];                       // 4 j-columns x 5 dims
#pragma unroll
        for (int d = 0; d < KD; ++d) {
            const float4 a = *(const float4*)(pa + d * B_SZ + jb);
            const float4 b = *(const float4*)(pb + d * B_SZ + jb);
            cj[d] = make_float4(a.x + b.x, a.y + b.y, a.z + b.z, a.w + b.w);
        }
#define PAIR_JJ(C, JJ)                                                           \
        {                                                                        \
            _Pragma("unroll")                                                    \
            for (int r = 0; r < 4; ++r) {                                        \
                const float s = __builtin_fabsf(mi[r][0] - cj[0].C)              \
                              + __builtin_fabsf(mi[r][1] - cj[1].C)              \
                              + __builtin_fabsf(mi[r][2] - cj[2].C)              \
                              + __builtin_fabsf(mi[r][3] - cj[3].C)              \
                              + __builtin_fabsf(mi[r][4] - cj[4].C);             \
                const float e = __builtin_amdgcn_exp2f(-s);                      \
                acci[r] += e;                                                    \
                colacc[c4 * 4 + JJ] += e;                                        \
            }                                                                    \
        }
        PAIR_JJ(x, 0) PAIR_JJ(y, 1) PAIR_JJ(z, 2) PAIR_JJ(w, 3)
#undef PAIR_JJ
    }

    // ---- full row sums: reduce across the 4 jg subgroups (xor bits 4,5)
#pragma unroll
    for (int r = 0; r < 4; ++r) {
        acci[r] += __shfl_xor(acci[r], 16, 64);
        acci[r] += __shfl_xor(acci[r], 32, 64);
    }
    // lane (jg,il) emits row bi + il*4 + jg  (bijective over 64 rows)
    const float rsum = (jg == 0) ? acci[0] : (jg == 1) ? acci[1]
                     : (jg == 2) ? acci[2] : acci[3];
    const int rrow = bi + il * 4 + jg;
    if (ATOMIC) atomicAdd(&out[(size_t)rrow * OUTW + F_SZ + k], rsum);
    else        part[(size_t)(k * NT + tj) * B_SZ + rrow] = rsum;

    // ---- column sums (off-diagonal): cross-il reduce via wave-local LDS
    if (!diag) {
#pragma unroll
        for (int q = 0; q < 16; ++q)
            colw[wv][jg * 16 + q][il] = colacc[q];    // conflict-free (pad 17)
        float csum = 0.0f;
#pragma unroll
        for (int i2 = 0; i2 < 16; ++i2)
            csum += colw[wv][lane][i2];               // 2 lanes/bank -> free
        if (ATOMIC) atomicAdd(&out[(size_t)(bj + lane) * OUTW + F_SZ + k], csum);
        else        part[(size_t)(k * NT + ti) * B_SZ + bj + lane] = csum;
    }
}

// ---------------------------------------------------------------------------
// K3: fold the 16 tile-source partials into out. grid 200 x 256.
// ---------------------------------------------------------------------------
__global__ __launch_bounds__(256) void reduce_kernel(const float* __restrict__ part,
                                                     float* __restrict__ out) {
    const int k = blockIdx.x >> 2;
    const int i = ((blockIdx.x & 3) << 8) | threadIdx.x;
    float s = 0.0f;
#pragma unroll
    for (int sp = 0; sp < NT; ++sp)
        s += part[((size_t)(k * NT + sp)) * B_SZ + i];
    out[(size_t)i * OUTW + F_SZ + k] = s;
}

// ---------------------------------------------------------------------------
extern "C" void kernel_launch(void* const* d_in, const int* in_sizes, int n_in,
                              void* d_out, int out_size, void* d_ws, size_t ws_size,
                              hipStream_t stream) {
    const float* x = (const float*)d_in[0];   // [1024, 512]
    const float* T = (const float*)d_in[1];   // [512, 250]
    float* out = (float*)d_out;               // [1024, 562]
    float* ws2 = (float*)d_ws;                // 2 SoA planes [250][1024]
    float* part = ws2 + 2 * (size_t)PLANE;    // [50][16][1024]

    const size_t need = (size_t)(2 * PLANE + PART_ELEMS) * 4;   // 5.3 MB
    const int fast = (ws_size >= need);

    gemm_copy_kernel<<<384, 256, 0, stream>>>(x, T, ws2, out, fast ? 0 : 1);

    if (fast) {
        pair_kernel<false><<<NK * PBLK, 256, 0, stream>>>(ws2, part, out);
        reduce_kernel<<<200, 256, 0, stream>>>(part, out);
    } else {
        pair_kernel<true><<<NK * PBLK, 256, 0, stream>>>(ws2, nullptr, out);
    }
}